// Round 6
// baseline (275.798 us; speedup 1.0000x reference)
//
#include <hip/hip_runtime.h>
#include <hip/hip_bf16.h>

// Problem constants
#define S_      1024
#define B_      2
#define H_      1024
#define E_      8
#define FFN_    1408
#define TWO_FFN 2816
#define T_      2048          // B_*S_
#define MAXSLOTS 5120

// prep partition: w1 transpose (704 tiles/expert, 8 tiles/block) + conv/gate
#define NB_T1   704            // w1: 5632 64x64 tiles / 8
#define NB_CONV 512
#define NB_PREP (NB_T1 + NB_CONV)

typedef float  f32x4 __attribute__((ext_vector_type(4)));
typedef short  s16x8 __attribute__((ext_vector_type(8)));

// ---------- helpers ----------
__device__ __forceinline__ unsigned short f2bf(float f) {
    unsigned u = __float_as_uint(f);
    u += 0x7fffu + ((u >> 16) & 1u);          // round-to-nearest-even
    return (unsigned short)(u >> 16);
}
__device__ __forceinline__ void async16(const void* g, void* l) {
    __builtin_amdgcn_global_load_lds(
        (const __attribute__((address_space(1))) unsigned int*)(unsigned long long)g,
        (__attribute__((address_space(3))) unsigned int*)(unsigned long long)l,
        16, 0, 0);
}
__device__ __forceinline__ size_t xrow_off(int t) {
    return (size_t)(t & (S_ - 1)) * (B_ * H_) + (size_t)(t >> 10) * H_;
}

// ---------- transpose core (64x64 tile, register-prefetch pipelined) ----------
__device__ __forceinline__ void tp_load(const float* __restrict__ ip, int C,
                                        int r0, int c0, int tid, float4* v) {
    int q = tid & 15, rr = tid >> 4;
#pragma unroll
    for (int i = 0; i < 4; i++)
        v[i] = *(const float4*)(ip + (size_t)(r0 + rr + 16 * i) * C + c0 + q * 4);
}
__device__ __forceinline__ void tp_to_lds(const float4* v, float (*lds)[65], int tid) {
    int q = tid & 15, rr = tid >> 4;
#pragma unroll
    for (int i = 0; i < 4; i++) {
        int r = rr + 16 * i;
        lds[q * 4 + 0][r] = v[i].x;
        lds[q * 4 + 1][r] = v[i].y;
        lds[q * 4 + 2][r] = v[i].z;
        lds[q * 4 + 3][r] = v[i].w;
    }
}
__device__ __forceinline__ void tp_store(unsigned short* __restrict__ op, int R,
                                         int r0, int c0, float (*lds)[65], int tid) {
    int oq = tid & 7, cc = tid >> 3;
#pragma unroll
    for (int i = 0; i < 2; i++) {
        int c = cc + 32 * i;
        const float* row = &lds[c][oq * 8];
        unsigned short o[8];
#pragma unroll
        for (int j = 0; j < 8; j++) o[j] = f2bf(row[j]);
        *(uint4*)(op + (size_t)(c0 + c) * R + r0 + oq * 8) = *(const uint4*)o;
    }
}

// ---------- 1. prep: w1 transpose (8 tiles/block, prefetched) + convert+gate ----------
__global__ __launch_bounds__(256) void k_prep(
    const float* __restrict__ hs, const float* __restrict__ gw,
    const float* __restrict__ w1,
    unsigned short* __restrict__ xb, unsigned short* __restrict__ w1bt,
    int* __restrict__ topkI, float* __restrict__ topkW) {
    __shared__ float tile[64][65];
    int bx = blockIdx.x, tid = threadIdx.x;
    if (bx < NB_T1) {
        // w1: R=1024(k), C=2816(n); per-expert tiles: 44 c x 16 r = 704
        float4 cur[4], nxt[4];
        int idx = bx * 8;
        int e = idx / 704, rem = idx % 704;
        int c0 = (rem % 44) * 64, r0 = (rem / 44) * 64;
        tp_load(w1 + (size_t)e * (H_ * TWO_FFN), TWO_FFN, r0, c0, tid, cur);
#pragma unroll
        for (int s = 0; s < 8; s++) {
            tp_to_lds(cur, tile, tid);
            __syncthreads();
            int e2 = 0, c2 = 0, r2 = 0;
            if (s < 7) {
                int idx2 = idx + s + 1;
                e2 = idx2 / 704; int rm2 = idx2 % 704;
                c2 = (rm2 % 44) * 64; r2 = (rm2 / 44) * 64;
                tp_load(w1 + (size_t)e2 * (H_ * TWO_FFN), TWO_FFN, r2, c2, tid, nxt);
            }
            tp_store(w1bt + (size_t)e * (H_ * TWO_FFN), H_, r0, c0, tile, tid);
            __syncthreads();
            e = e2; c0 = c2; r0 = r2;
#pragma unroll
            for (int i = 0; i < 4; i++) cur[i] = nxt[i];
        }
        return;
    }
    // convert + gate
    int cb = bx - NB_T1;
    int wid = tid >> 6, lane = tid & 63;
    int t = cb * 4 + wid;
    const float* xr = hs + xrow_off(t);
    unsigned short* xo = xb + (size_t)t * H_;
    float acc[E_];
#pragma unroll
    for (int e = 0; e < E_; e++) acc[e] = 0.f;
#pragma unroll
    for (int p = 0; p < 4; p++) {
        int h = p * 256 + lane * 4;
        const float4 v = *(const float4*)(xr + h);
        unsigned short o[4] = { f2bf(v.x), f2bf(v.y), f2bf(v.z), f2bf(v.w) };
        *(uint2*)(xo + h) = *(const uint2*)o;
#pragma unroll
        for (int e = 0; e < E_; e++) {
            const float4 g = *(const float4*)(gw + e * H_ + h);
            acc[e] += v.x * g.x + v.y * g.y + v.z * g.z + v.w * g.w;
        }
    }
#pragma unroll
    for (int e = 0; e < E_; e++)
        for (int off = 32; off > 0; off >>= 1) acc[e] += __shfl_down(acc[e], off);
    if (lane == 0) {
        float l0 = -1e30f, l1 = -1e30f; int i0 = 0, i1 = 0;
#pragma unroll
        for (int e = 0; e < E_; e++) {
            float v = acc[e];
            if (v > l0)      { l1 = l0; i1 = i0; l0 = v; i0 = e; }
            else if (v > l1) { l1 = v;  i1 = e; }
        }
        float p1 = expf(l1 - l0);                 // p0 = 1
        float w0 = 1.f / (1.f + p1);
        float w1s = 1.f - w0;
        topkI[2 * t] = i0; topkI[2 * t + 1] = i1;
        topkW[2 * t] = w0; topkW[2 * t + 1] = w1s;
    }
}

// ---------- 2. histogram + route + assign (one block, 1024 thr) ----------
// ctrl ints: [40+e]=ntile(e)  [48+e]=slotBase(e)
__global__ void k_routeassign(const int* __restrict__ topkI, const float* __restrict__ topkW,
                              int* __restrict__ ctrl, int* __restrict__ perm,
                              float* __restrict__ wgt) {
    __shared__ int s_wcnt[16][E_];
    __shared__ int s_base[E_];
    __shared__ int s_cur[E_];
    int tid = threadIdx.x, wid = tid >> 6, lane = tid & 63;
    int cnt[E_];
#pragma unroll
    for (int j = 0; j < E_; j++) cnt[j] = 0;
    for (int i = tid; i < 2 * T_; i += 1024) {
        int e = topkI[i];
#pragma unroll
        for (int j = 0; j < E_; j++) cnt[j] += (e == j);
    }
#pragma unroll
    for (int j = 0; j < E_; j++)
        for (int off = 32; off > 0; off >>= 1) cnt[j] += __shfl_down(cnt[j], off);
    if (lane == 0) {
#pragma unroll
        for (int j = 0; j < E_; j++) s_wcnt[wid][j] = cnt[j];
    }
    __syncthreads();
    if (tid == 0) {
        int b = 0;
        for (int e = 0; e < E_; e++) {
            int n = 0;
            for (int w = 0; w < 16; w++) n += s_wcnt[w][e];
            int ntile = (n + 127) >> 7;
            s_base[e] = b;
            ctrl[40 + e] = ntile;
            ctrl[48 + e] = b;
            b += ntile * 128;
        }
#pragma unroll
        for (int e = 0; e < E_; e++) s_cur[e] = 0;
    }
    __syncthreads();
    for (int s = tid; s < MAXSLOTS; s += 1024) { perm[s] = 0; wgt[s] = 0.f; }
    __syncthreads();
    for (int t = tid; t < T_; t += 1024) {
#pragma unroll
        for (int k = 0; k < 2; k++) {
            int e = topkI[2 * t + k];
            int pos = atomicAdd(&s_cur[e], 1);   // LDS atomic
            int slot = s_base[e] + pos;
            perm[slot] = t;
            wgt[slot]  = topkW[2 * t + k];
        }
    }
}

// ---------- 3. GEMM1 (+swiglu epilogue)  ||  w2 transpose (same launch) ----------
// y<16: gemm tile; y in {16,17}: w2 transpose blocks (dispatched last, fill idle CUs).
__global__ __launch_bounds__(256) void k_gemm1x(
    const unsigned short* __restrict__ xb, const unsigned short* __restrict__ w1bt,
    const float* __restrict__ w2, unsigned short* __restrict__ w2bt,
    const int* __restrict__ ctrl, const int* __restrict__ perm,
    unsigned short* __restrict__ A2) {
    __shared__ __align__(16) unsigned short smem[2 * 128 * 64];   // 32 KB
    int tid = threadIdx.x;
    if (blockIdx.y >= 16) {
        // ---- w2 transpose: R=1408(k), C=1024(n); per-expert tiles 16c x 22r = 352
        float (*tile)[65] = (float(*)[65])smem;
        int tb = blockIdx.x + 176 * (blockIdx.y - 16);   // 0..351, 8 tiles each
        float4 cur[4], nxt[4];
        int idx = tb * 8;
        int e = idx / 352, rem = idx % 352;
        int c0 = (rem & 15) * 64, r0 = (rem >> 4) * 64;
        tp_load(w2 + (size_t)e * (FFN_ * H_), H_, r0, c0, tid, cur);
#pragma unroll
        for (int s = 0; s < 8; s++) {
            tp_to_lds(cur, tile, tid);
            __syncthreads();
            int e2 = 0, c2 = 0, r2 = 0;
            if (s < 7) {
                int idx2 = idx + s + 1;
                e2 = idx2 / 352; int rm2 = idx2 % 352;
                c2 = (rm2 & 15) * 64; r2 = (rm2 >> 4) * 64;
                tp_load(w2 + (size_t)e2 * (FFN_ * H_), H_, r2, c2, tid, nxt);
            }
            tp_store(w2bt + (size_t)e * (FFN_ * H_), FFN_, r0, c0, tile, tid);
            __syncthreads();
            e = e2; c0 = c2; r0 = r2;
#pragma unroll
            for (int i = 0; i < 4; i++) cur[i] = nxt[i];
        }
        return;
    }
    // ---- gemm1: x = e + 8*ct (ct 0..21), y = tile-in-expert
    int e  = blockIdx.x & 7;
    int ct = blockIdx.x >> 3;
    int ti = blockIdx.y;
    if (ti >= ctrl[40 + e]) return;
    int slot0 = ctrl[48 + e] + ti * 128;
    unsigned short* As = smem;
    unsigned short* Bs = smem + 128 * 64;
    int wid = tid >> 6, lane = tid & 63;

    const unsigned short* aPtr[4];
    const unsigned short* bPtr[4];
    unsigned short* lA[4];
    unsigned short* lB[4];
#pragma unroll
    for (int i = 0; i < 4; i++) {
        int c = (wid * 4 + i) * 64 + lane;      // chunk id 0..1023
        int r = c >> 3;
        int qd = (c & 7) ^ (r & 7);             // XOR swizzle
        int col8 = qd * 8;
        int tok = perm[slot0 + r];
        int gr = (r < 64) ? (ct * 64 + r) : (FFN_ + ct * 64 + (r - 64));
        aPtr[i] = xb + (size_t)tok * H_ + col8;
        bPtr[i] = w1bt + ((size_t)e * TWO_FFN + gr) * H_ + col8;
        lA[i] = As + (size_t)c * 8;
        lB[i] = Bs + (size_t)c * 8;
    }
    f32x4 acc[4][4];
#pragma unroll
    for (int mi = 0; mi < 4; mi++)
#pragma unroll
        for (int ni = 0; ni < 4; ni++) acc[mi][ni] = (f32x4){0.f, 0.f, 0.f, 0.f};
    int wm = wid & 1, wn = wid >> 1;
    int rowB = wm * 64, colB = wn * 64;
    int sw = (lane & 7) << 3;

    for (int k0 = 0; k0 < H_; k0 += 64) {
#pragma unroll
        for (int i = 0; i < 4; i++) { async16(aPtr[i] + k0, lA[i]); async16(bPtr[i] + k0, lB[i]); }
        __syncthreads();
#pragma unroll
        for (int kk = 0; kk < 64; kk += 32) {
            int kr = (kk + ((lane >> 4) << 3)) ^ sw;
            s16x8 af[4], bf[4];
#pragma unroll
            for (int mi = 0; mi < 4; mi++) af[mi] = *(const s16x8*)&As[(rowB + mi * 16 + (lane & 15)) * 64 + kr];
#pragma unroll
            for (int ni = 0; ni < 4; ni++) bf[ni] = *(const s16x8*)&Bs[(colB + ni * 16 + (lane & 15)) * 64 + kr];
#pragma unroll
            for (int mi = 0; mi < 4; mi++)
#pragma unroll
                for (int ni = 0; ni < 4; ni++)
                    acc[mi][ni] = __builtin_amdgcn_mfma_f32_16x16x32_bf16(af[mi], bf[ni], acc[mi][ni], 0, 0, 0);
        }
        __syncthreads();
    }
    // ---- fused swiglu epilogue ----
    float* upLds = (float*)smem;
    if (wn == 1) {
#pragma unroll
        for (int mi = 0; mi < 4; mi++)
#pragma unroll
            for (int ni = 0; ni < 4; ni++)
#pragma unroll
                for (int r = 0; r < 4; r++) {
                    int m = rowB + mi * 16 + (lane >> 4) * 4 + r;
                    int u = ni * 16 + (lane & 15);
                    upLds[m * 64 + u] = acc[mi][ni][r];
                }
    }
    __syncthreads();
    if (wn == 0) {
#pragma unroll
        for (int mi = 0; mi < 4; mi++)
#pragma unroll
            for (int r = 0; r < 4; r++) {
                int m = rowB + mi * 16 + (lane >> 4) * 4 + r;
                unsigned short* arow = A2 + (size_t)(slot0 + m) * FFN_ + ct * 64;
#pragma unroll
                for (int ni = 0; ni < 4; ni++) {
                    int gl = ni * 16 + (lane & 15);
                    float g = acc[mi][ni][r];
                    float u = upLds[m * 64 + gl];
                    float s = g / (1.f + expf(-g));
                    arow[gl] = f2bf(s * u);
                }
            }
    }
}

// ---------- 4. GEMM2 + fused weighted combine (fp32 atomics into zeroed out) ----------
// Grid: x = e + 8*hct (hct 0..31, 32-wide H tiles), y = tile (16). No split-K.
__global__ __launch_bounds__(256) void k_gemm2f(
    const unsigned short* __restrict__ A2, const unsigned short* __restrict__ w2bt,
    const int* __restrict__ ctrl, const int* __restrict__ perm,
    const float* __restrict__ wgt, float* __restrict__ out) {
    int e   = blockIdx.x & 7;
    int hct = blockIdx.x >> 3;                  // 0..31
    int ti  = blockIdx.y;
    if (ti >= ctrl[40 + e]) return;
    int slot0 = ctrl[48 + e] + ti * 128;
    __shared__ __align__(16) unsigned short As[128 * 64];   // 16 KB
    __shared__ __align__(16) unsigned short Bs[32 * 64];    // 4 KB
    int tid = threadIdx.x, wid = tid >> 6, lane = tid & 63;

    const unsigned short* aPtr[4];
    unsigned short* lA[4];
#pragma unroll
    for (int i = 0; i < 4; i++) {
        int c = (wid * 4 + i) * 64 + lane;
        int r = c >> 3;
        int col8 = ((c & 7) ^ (r & 7)) * 8;
        aPtr[i] = A2 + (size_t)(slot0 + r) * FFN_ + col8;
        lA[i] = As + (size_t)c * 8;
    }
    // B: 32 rows x 64 k = 256 chunks, exactly 1 per thread
    int cB = tid, rB2 = cB >> 3;
    int colB8 = ((cB & 7) ^ (rB2 & 7)) * 8;
    const unsigned short* bPtr = w2bt + ((size_t)e * H_ + hct * 32 + rB2) * FFN_ + colB8;
    unsigned short* lB = Bs + (size_t)cB * 8;

    f32x4 acc[2][2];
#pragma unroll
    for (int mi = 0; mi < 2; mi++)
#pragma unroll
        for (int ni = 0; ni < 2; ni++) acc[mi][ni] = (f32x4){0.f, 0.f, 0.f, 0.f};
    int rowB = wid * 32;                        // wave m-quarter
    int sw = (lane & 7) << 3;

    for (int k0 = 0; k0 < FFN_; k0 += 64) {     // 22 steps
#pragma unroll
        for (int i = 0; i < 4; i++) async16(aPtr[i] + k0, lA[i]);
        async16(bPtr + k0, lB);
        __syncthreads();
#pragma unroll
        for (int kk = 0; kk < 64; kk += 32) {
            int kr = (kk + ((lane >> 4) << 3)) ^ sw;
            s16x8 af[2], bf[2];
#pragma unroll
            for (int mi = 0; mi < 2; mi++) af[mi] = *(const s16x8*)&As[(rowB + mi * 16 + (lane & 15)) * 64 + kr];
#pragma unroll
            for (int ni = 0; ni < 2; ni++) bf[ni] = *(const s16x8*)&Bs[(ni * 16 + (lane & 15)) * 64 + kr];
#pragma unroll
            for (int mi = 0; mi < 2; mi++)
#pragma unroll
                for (int ni = 0; ni < 2; ni++)
                    acc[mi][ni] = __builtin_amdgcn_mfma_f32_16x16x32_bf16(af[mi], bf[ni], acc[mi][ni], 0, 0, 0);
        }
        __syncthreads();
    }
    // fused combine: out[tok][hct*32 + n] += wgt[slot] * acc
#pragma unroll
    for (int mi = 0; mi < 2; mi++)
#pragma unroll
        for (int r = 0; r < 4; r++) {
            int m = rowB + mi * 16 + (lane >> 4) * 4 + r;
            int slot = slot0 + m;
            float wv = wgt[slot];
            if (wv != 0.f) {
                int tok = perm[slot];
                float* orow = out + xrow_off(tok) + hct * 32;
#pragma unroll
                for (int ni = 0; ni < 2; ni++)
                    atomicAdd(&orow[ni * 16 + (lane & 15)], wv * acc[mi][ni][r]);
            }
        }
}

extern "C" void kernel_launch(void* const* d_in, const int* in_sizes, int n_in,
                              void* d_out, int out_size, void* d_ws, size_t ws_size,
                              hipStream_t stream) {
    (void)in_sizes; (void)n_in; (void)ws_size;
    const float* hs = (const float*)d_in[0];
    const float* gw = (const float*)d_in[1];
    const float* w1 = (const float*)d_in[2];
    const float* w2 = (const float*)d_in[3];
    float* out = (float*)d_out;
    char* ws = (char*)d_ws;

    int*            ctrl  = (int*)ws;                                   // 1 KB
    int*            topkI = (int*)(ws + (16u << 10));                   // 16 KB
    float*          topkW = (float*)(ws + (48u << 10));                 // 16 KB
    int*            perm  = (int*)(ws + (80u << 10));                   // 20 KB
    float*          wgt   = (float*)(ws + (112u << 10));                // 20 KB
    unsigned short* xb    = (unsigned short*)(ws + (1ull  << 20));      // 4 MiB
    unsigned short* w1bt  = (unsigned short*)(ws + (5ull  << 20));      // 44 MiB
    unsigned short* w2bt  = (unsigned short*)(ws + (49ull << 20));      // 22 MiB
    unsigned short* A2    = (unsigned short*)(ws + (71ull << 20));      // 13.75 MiB -> ~85 MiB

    hipMemsetAsync(out, 0, (size_t)out_size * sizeof(float), stream);
    k_prep<<<NB_PREP, 256, 0, stream>>>(hs, gw, w1, xb, w1bt, topkI, topkW);
    k_routeassign<<<1, 1024, 0, stream>>>(topkI, topkW, ctrl, perm, wgt);
    k_gemm1x<<<dim3(176, 18), 256, 0, stream>>>(xb, w1bt, w2, w2bt, ctrl, perm, A2);
    k_gemm2f<<<dim3(256, 16), 256, 0, stream>>>(A2, w2bt, ctrl, perm, wgt, out);
}